// Round 4
// baseline (119.216 us; speedup 1.0000x reference)
//
#include <hip/hip_runtime.h>

// RobustAttention: blockwise (w=15) causal cosFormer linear attention.
// scores[l,j] = cos(th_l - th_j) * <relu(q_l), relu(k_j)>, j<=l
// out[l] = sum_j scores[l,j] * relu(v_j) / max(sum_j scores[l,j], 1e-6)
//
// R7: R6 proved occupancy is NOT the limiter (2->4 blocks/CU: dur flat,
// measured occupancy flat at 18%). The arithmetic points at the vector-
// memory REQUEST path: phase-1 q loads are per-lane 256B rows at stride
// 256B -> each dwordx4 presents 60 distinct 64B lines to the TA (vs 16
// coalesced), and 16 c-iterations re-request the same lines: 960 line-
// requests/wave for 240 unique lines = 57% of total request traffic.
// Fix: q goes through LDS like k.
//  - ONE 65,280 B buffer, time-multiplexed: stage relu(q) coalesced into
//    a row-padded layout (+1 float4/row) -> lanes read their row from LDS
//    (stride 68 floats = 4-bank lane stride, 2-way conflict = free) into
//    regs -> restage relu(k) (full tile, phase 1 unsplit) -> dots.
//  - LDS 64KB caps at 2 blocks/CU — R6 proved that's free. In exchange the
//    VGPR budget is wide open (<=256), so relu(v) loads are HOISTED to the
//    top: their HBM latency hides under both staging passes + phase 1.
//  - All global traffic now coalesced (16 lines/instr); requests/wave
//    drop 1680 -> 960.
//  - NT output stores kept.

namespace {

constexpr int W        = 15;            // block_size (rows per tile)
constexpr int CH       = 16;            // float4 per row (D=64)
constexpr int TILE4    = W * CH;        // 240 float4 per tile
constexpr int TPG      = 16;            // tiles per workgroup
constexpr int NTHREADS = 256;
constexpr int RSTRIDE4 = CH + 1;        // 17: padded row stride (float4)
constexpr int TSTRIDE4 = W * RSTRIDE4;  // 255: padded tile stride (float4)

typedef float f32x4_n __attribute__((ext_vector_type(4)));

__device__ __forceinline__ float4 relu4(float4 a) {
    return make_float4(fmaxf(a.x, 0.f), fmaxf(a.y, 0.f),
                       fmaxf(a.z, 0.f), fmaxf(a.w, 0.f));
}

__global__ __launch_bounds__(NTHREADS, 2)
void robust_attn_kernel(const float4* __restrict__ q4,
                        const float4* __restrict__ k4,
                        const float4* __restrict__ v4,
                        float4* __restrict__ o4,
                        int nblocks)
{
    __shared__ float4 lds[TPG * TSTRIDE4];   // 16*255*16 = 65,280 B

    const int tid  = threadIdx.x;
    const int lane = tid & 15;                 // row l (ph1) / d-chunk (ph2)
    const int t    = tid >> 4;                 // tile within WG
    const int g0   = blockIdx.x * TPG;
    const int g    = g0 + t;
    const bool active = (g < nblocks);
    const bool ph1    = active && (lane < W);

    // ---------- hoist relu(v): coalesced, latency hides under staging ------
    float4 vv[W];
    if (active) {
        const float4* __restrict__ vp = v4 + (size_t)g * TILE4 + lane;
#pragma unroll
        for (int j = 0; j < W; ++j) vv[j] = relu4(vp[j * CH]);
    }

    // ---------- stage relu(q) into LDS, row-padded layout ------------------
    {
        const size_t base = (size_t)g0 * TILE4;
#pragma unroll
        for (int r = 0; r < (TPG * TILE4) / NTHREADS; ++r) {   // 15 iters
            const int idx = tid + r * NTHREADS;
            const int tt  = idx / TILE4;
            const int pos = idx - tt * TILE4;
            const int rr  = pos >> 4;          // row within tile
            const int cc  = pos & 15;          // float4 within row
            float4 x = make_float4(0.f, 0.f, 0.f, 0.f);
            if (g0 + tt < nblocks) x = q4[base + idx];
            lds[tt * TSTRIDE4 + rr * RSTRIDE4 + cc] = relu4(x);
        }
    }
    __syncthreads();

    // ---------- each ph1 lane pulls its q row from LDS ---------------------
    float4 qr[CH];
    if (ph1) {
        const float4* __restrict__ ql = &lds[t * TSTRIDE4 + lane * RSTRIDE4];
#pragma unroll
        for (int c = 0; c < CH; ++c) qr[c] = ql[c];
    }
    __syncthreads();   // all q reads done before k overwrites the buffer

    // ---------- restage relu(k) into the same buffer -----------------------
    {
        const size_t base = (size_t)g0 * TILE4;
#pragma unroll
        for (int r = 0; r < (TPG * TILE4) / NTHREADS; ++r) {   // 15 iters
            const int idx = tid + r * NTHREADS;
            const int tt  = idx / TILE4;
            const int pos = idx - tt * TILE4;
            const int rr  = pos >> 4;
            const int cc  = pos & 15;
            float4 x = make_float4(0.f, 0.f, 0.f, 0.f);
            if (g0 + tt < nblocks) x = k4[base + idx];
            lds[tt * TSTRIDE4 + rr * RSTRIDE4 + cc] = relu4(x);
        }
    }
    __syncthreads();

    // ---------- phase 1: dots (k broadcast from LDS), weights, normalize ---
    float s[W];
#pragma unroll
    for (int j = 0; j < W; ++j) s[j] = 0.f;

    if (ph1) {
        const int l = lane;
        const float4* __restrict__ kl = &lds[t * TSTRIDE4];
#pragma unroll
        for (int j = 0; j < W; ++j) {
            float acc = 0.f;
#pragma unroll
            for (int c = 0; c < CH; ++c) {
                const float4 kk = kl[j * RSTRIDE4 + c];
                acc = fmaf(qr[c].x, kk.x, acc);
                acc = fmaf(qr[c].y, kk.y, acc);
                acc = fmaf(qr[c].z, kk.z, acc);
                acc = fmaf(qr[c].w, kk.w, acc);
            }
            s[j] = acc;
        }

        const float step = 1.57079632679489662f / (float)W;  // (pi/2)/15
        float denom = 0.f;
#pragma unroll
        for (int j = 0; j < W; ++j) {
            float wc = __cosf(step * (float)(l - j));
            float tv = (j <= l) ? s[j] * wc : 0.f;
            s[j] = tv;
            denom += tv;
        }
        const float inv = 1.f / fmaxf(denom, 1e-6f);
#pragma unroll
        for (int j = 0; j < W; ++j) s[j] *= inv;
    }

    // ---------- phase 2: out = S @ relu(v); weights via wave shuffle -------
    if (active) {
        float4* __restrict__ op = o4 + (size_t)g * TILE4 + lane;

        const int tbase = tid & 48;   // tile base lane within the wave
#pragma unroll
        for (int l = 0; l < W; ++l) {
            float ax = 0.f, ay = 0.f, az = 0.f, aw = 0.f;
#pragma unroll
            for (int j = 0; j <= l; ++j) {     // causal
                const float w = __shfl(s[j], tbase + l, 64);
                ax = fmaf(w, vv[j].x, ax);
                ay = fmaf(w, vv[j].y, ay);
                az = fmaf(w, vv[j].z, az);
                aw = fmaf(w, vv[j].w, aw);
            }
            // nontemporal: output stream must not evict L3-resident inputs
            f32x4_n val = {ax, ay, az, aw};
            __builtin_nontemporal_store(val, (f32x4_n*)(op + l * CH));
        }
    }
}

}  // namespace

extern "C" void kernel_launch(void* const* d_in, const int* in_sizes, int n_in,
                              void* d_out, int out_size, void* d_ws, size_t ws_size,
                              hipStream_t stream) {
    const float4* q = (const float4*)d_in[0];
    const float4* k = (const float4*)d_in[1];
    const float4* v = (const float4*)d_in[2];
    float4* out = (float4*)d_out;

    const int total   = in_sizes[0];           // B*H*L*D
    const int nblocks = total / (W * CH * 4);  // 20480 for the bench shape
    const int wgs     = (nblocks + TPG - 1) / TPG;

    robust_attn_kernel<<<wgs, NTHREADS, 0, stream>>>(q, k, v, out, nblocks);
}

// Round 5
// 73.624 us; speedup vs baseline: 1.6193x; 1.6193x over previous
//
#include <hip/hip_runtime.h>

// RobustAttention: blockwise (w=15) causal cosFormer linear attention.
// scores[l,j] = cos(th_l - th_j) * <relu(q_l), relu(k_j)>, j<=l
// out[l] = sum_j scores[l,j] * relu(v_j) / max(sum_j scores[l,j], 1e-6)
//
// R8: R7's q-through-LDS was never actually tested — the vv[15] hoist
// spilled (WRITE_SIZE 76.8 -> 154.5 MB; the +77.7 MB is exactly 240 B x
// 327,680 threads = the hoisted array). Third spill in four rounds, same
// root cause: the kernel lives at ~110 VGPRs and any 60-reg array held
// across a barrier tips the allocator into scratch.
// R8 = R7 minus the hoist. v loads back at phase-2 start (R6's proven
// 88-VGPR placement). This isolates the q-coalescing hypothesis:
//  - q staged coalesced into row-padded LDS (16 lines/instr vs 60
//    scattered lines/instr x 16 redundant issues in R3/R6), lanes pull
//    their 256-B q row from LDS (stride 17 float4: 2-way bank = free).
//  - Same 65,280 B buffer then restaged with relu(k); phase 1 unsplit.
//  - 2 blocks/CU (R6 proved 2 vs 4 blocks is perf-neutral).
//  - NT output stores kept.
// Pass/fail: WRITE_SIZE must be 76,800 KB. Then dur tells us whether the
// scattered-q request path was the real limiter.

namespace {

constexpr int W        = 15;            // block_size (rows per tile)
constexpr int CH       = 16;            // float4 per row (D=64)
constexpr int TILE4    = W * CH;        // 240 float4 per tile
constexpr int TPG      = 16;            // tiles per workgroup
constexpr int NTHREADS = 256;
constexpr int RSTRIDE4 = CH + 1;        // 17: padded row stride (float4)
constexpr int TSTRIDE4 = W * RSTRIDE4;  // 255: padded tile stride (float4)

typedef float f32x4_n __attribute__((ext_vector_type(4)));

__device__ __forceinline__ float4 relu4(float4 a) {
    return make_float4(fmaxf(a.x, 0.f), fmaxf(a.y, 0.f),
                       fmaxf(a.z, 0.f), fmaxf(a.w, 0.f));
}

__global__ __launch_bounds__(NTHREADS, 2)
void robust_attn_kernel(const float4* __restrict__ q4,
                        const float4* __restrict__ k4,
                        const float4* __restrict__ v4,
                        float4* __restrict__ o4,
                        int nblocks)
{
    __shared__ float4 lds[TPG * TSTRIDE4];   // 16*255*16 = 65,280 B

    const int tid  = threadIdx.x;
    const int lane = tid & 15;                 // row l (ph1) / d-chunk (ph2)
    const int t    = tid >> 4;                 // tile within WG
    const int g0   = blockIdx.x * TPG;
    const int g    = g0 + t;
    const bool active = (g < nblocks);
    const bool ph1    = active && (lane < W);

    // ---------- stage relu(q) into LDS, row-padded layout ------------------
    {
        const size_t base = (size_t)g0 * TILE4;
#pragma unroll
        for (int r = 0; r < (TPG * TILE4) / NTHREADS; ++r) {   // 15 iters
            const int idx = tid + r * NTHREADS;
            const int tt  = idx / TILE4;
            const int pos = idx - tt * TILE4;
            const int rr  = pos >> 4;          // row within tile
            const int cc  = pos & 15;          // float4 within row
            float4 x = make_float4(0.f, 0.f, 0.f, 0.f);
            if (g0 + tt < nblocks) x = q4[base + idx];
            lds[tt * TSTRIDE4 + rr * RSTRIDE4 + cc] = relu4(x);
        }
    }
    __syncthreads();

    // ---------- each ph1 lane pulls its q row from LDS ---------------------
    float4 qr[CH];
    if (ph1) {
        const float4* __restrict__ ql = &lds[t * TSTRIDE4 + lane * RSTRIDE4];
#pragma unroll
        for (int c = 0; c < CH; ++c) qr[c] = ql[c];
    }
    __syncthreads();   // all q reads done before k overwrites the buffer

    // ---------- restage relu(k) into the same buffer -----------------------
    {
        const size_t base = (size_t)g0 * TILE4;
#pragma unroll
        for (int r = 0; r < (TPG * TILE4) / NTHREADS; ++r) {   // 15 iters
            const int idx = tid + r * NTHREADS;
            const int tt  = idx / TILE4;
            const int pos = idx - tt * TILE4;
            const int rr  = pos >> 4;
            const int cc  = pos & 15;
            float4 x = make_float4(0.f, 0.f, 0.f, 0.f);
            if (g0 + tt < nblocks) x = k4[base + idx];
            lds[tt * TSTRIDE4 + rr * RSTRIDE4 + cc] = relu4(x);
        }
    }
    __syncthreads();

    // ---------- phase 1: dots (k broadcast from LDS), weights, normalize ---
    float s[W];
#pragma unroll
    for (int j = 0; j < W; ++j) s[j] = 0.f;

    if (ph1) {
        const int l = lane;
        const float4* __restrict__ kl = &lds[t * TSTRIDE4];
#pragma unroll
        for (int j = 0; j < W; ++j) {
            float acc = 0.f;
#pragma unroll
            for (int c = 0; c < CH; ++c) {
                const float4 kk = kl[j * RSTRIDE4 + c];
                acc = fmaf(qr[c].x, kk.x, acc);
                acc = fmaf(qr[c].y, kk.y, acc);
                acc = fmaf(qr[c].z, kk.z, acc);
                acc = fmaf(qr[c].w, kk.w, acc);
            }
            s[j] = acc;
        }

        const float step = 1.57079632679489662f / (float)W;  // (pi/2)/15
        float denom = 0.f;
#pragma unroll
        for (int j = 0; j < W; ++j) {
            float wc = __cosf(step * (float)(l - j));
            float tv = (j <= l) ? s[j] * wc : 0.f;
            s[j] = tv;
            denom += tv;
        }
        const float inv = 1.f / fmaxf(denom, 1e-6f);
#pragma unroll
        for (int j = 0; j < W; ++j) s[j] *= inv;
    }

    // ---------- phase 2: out = S @ relu(v); weights via wave shuffle -------
    if (active) {
        const float4* __restrict__ vp = v4 + (size_t)g * TILE4 + lane;
        float4* __restrict__ op       = o4 + (size_t)g * TILE4 + lane;

        float4 vv[W];
#pragma unroll
        for (int j = 0; j < W; ++j) vv[j] = relu4(vp[j * CH]);

        const int tbase = tid & 48;   // tile base lane within the wave
#pragma unroll
        for (int l = 0; l < W; ++l) {
            float ax = 0.f, ay = 0.f, az = 0.f, aw = 0.f;
#pragma unroll
            for (int j = 0; j <= l; ++j) {     // causal
                const float w = __shfl(s[j], tbase + l, 64);
                ax = fmaf(w, vv[j].x, ax);
                ay = fmaf(w, vv[j].y, ay);
                az = fmaf(w, vv[j].z, az);
                aw = fmaf(w, vv[j].w, aw);
            }
            // nontemporal: output stream must not evict L3-resident inputs
            f32x4_n val = {ax, ay, az, aw};
            __builtin_nontemporal_store(val, (f32x4_n*)(op + l * CH));
        }
    }
}

}  // namespace

extern "C" void kernel_launch(void* const* d_in, const int* in_sizes, int n_in,
                              void* d_out, int out_size, void* d_ws, size_t ws_size,
                              hipStream_t stream) {
    const float4* q = (const float4*)d_in[0];
    const float4* k = (const float4*)d_in[1];
    const float4* v = (const float4*)d_in[2];
    float4* out = (float4*)d_out;

    const int total   = in_sizes[0];           // B*H*L*D
    const int nblocks = total / (W * CH * 4);  // 20480 for the bench shape
    const int wgs     = (nblocks + TPG - 1) / TPG;

    robust_attn_kernel<<<wgs, NTHREADS, 0, stream>>>(q, k, v, out, nblocks);
}